// Round 9
// baseline (63.847 us; speedup 1.0000x reference)
//
#include <hip/hip_runtime.h>
#include <hip/hip_bf16.h>
#include <stdint.h>

#define LRELU_ALPHA 0.2f
#define NEG_INF -9000000000000000.0f
#define NB 32768
#define NTASKS (NB/16)
#define GRID_A 768

typedef float f32x4 __attribute__((ext_vector_type(4)));
typedef short s16x8 __attribute__((ext_vector_type(8)));
typedef short s16x4 __attribute__((ext_vector_type(4)));

__device__ __forceinline__ unsigned short f2bf(float f){
  unsigned int u = __float_as_uint(f);
  u += 0x7fffu + ((u >> 16) & 1u);
  return (unsigned short)(u >> 16);
}
__device__ __forceinline__ float bf2f(short s){
  return __uint_as_float(((unsigned int)(unsigned short)s) << 16);
}

// ws layout: ushort [0,16384): W^T bf16 swizzled; ushort [16384,20480): e-tile (fallback only)
//            float  idx 10240..10432 (bytes 40960..41728): v1,v2,v3 = W2eff @ {a2S,a2D,fc_w}
//            ushort idx 32768+ (byte 65536+): WhT bf16, [b][c][j], 256 ushorts per graph (16MB)
__global__ void prep_kernel(const float* __restrict__ W, const float* __restrict__ W2,
                            const float* __restrict__ a, const float* __restrict__ a2,
                            const float* __restrict__ fc_w,
                            unsigned short* __restrict__ wsp){
  int t = blockIdx.x * blockDim.x + threadIdx.x;
  if (t < 64*256){
    int o = t & 63, k = t >> 6;
    wsp[o*256 + (k ^ ((o & 7) << 3))] = f2bf(W[k*64 + o]);
  }
  if (t < 16*256){
    int o = t & 15, k = t >> 4;
    float v = 0.f;
    if (o == 0){ for (int c = 0; c < 64; ++c) v += W[k*64 + c]*a[c]; }
    else if (o == 1){ for (int c = 0; c < 64; ++c) v += W[k*64 + c]*a[64 + c]; }
    wsp[16384 + o*256 + (k ^ ((o & 7) << 3))] = f2bf(v);
  }
  if (t < 192){
    int which = t >> 6, c = t & 63;
    const float* vec = (which == 0) ? a2 : (which == 1) ? (a2 + 64) : fc_w;
    float s = 0.f;
    for (int o = 0; o < 64; ++o){
      float w2e = 0.f;
      #pragma unroll
      for (int h = 0; h < 8; ++h) w2e += W2[(h*64 + c)*64 + o];
      s += w2e * vec[o];
    }
    ((float*)wsp)[10240 + t] = s;
  }
}

// ================= Phase A: Wh = x @ W, tiny epilogue =================
// Chunked K=128 staging: xb[8] (32 VGPR) single-buffer; LDS 48KB -> 3 blocks/CU.
__launch_bounds__(256, 3)
__global__ void gemm_kernel(const float* __restrict__ x,
                            const unsigned short* __restrict__ wsp,
                            unsigned short* __restrict__ whT){
  __shared__ __align__(16) unsigned short smem[24576]; // [0,16384) W^T ; [16384,24576) x-tiles 4x2048
  const int tid  = threadIdx.x;
  const int lane = tid & 63;
  const int p  = tid & 15;
  const int g  = (tid >> 4) & 3;
  const int wv = tid >> 6;
  const int xb_base = 16384 + wv*2048;
  const int r_st = lane >> 5;          // row parity
  const int kq   = (lane & 31) * 4;    // k-quad (floats) within chunk

  float4 xb[8];
  {
    const int b0 = blockIdx.x*16 + wv*4;
    const float* src = x + (size_t)b0*1024;
    #pragma unroll
    for (int t = 0; t < 8; ++t)
      xb[t] = *(const float4*)(src + (2*t + r_st)*256 + (lane & 31)*4);
  }
  { // stage W^T (32KB, L2-resident source)
    const uint4* src = (const uint4*)wsp;
    uint4* dst = (uint4*)smem;
    #pragma unroll
    for (int i = 0; i < 8; ++i) dst[tid + 256*i] = src[tid + 256*i];
  }
  __syncthreads();

  for (int it = blockIdx.x; it < NTASKS; it += GRID_A){
    const int b0 = it*16 + wv*4;
    f32x4 acc[4];
    #pragma unroll
    for (int ct = 0; ct < 4; ++ct) acc[ct] = (f32x4){0.f,0.f,0.f,0.f};

    #pragma unroll
    for (int cb = 0; cb < 2; ++cb){
      // stage chunk cb (consumes xb)
      #pragma unroll
      for (int t = 0; t < 8; ++t){
        const int r = 2*t + r_st;
        union { s16x4 s; __hip_bfloat162 h2[2]; } w;
        w.h2[0] = __float22bfloat162_rn(make_float2(xb[t].x, xb[t].y));
        w.h2[1] = __float22bfloat162_rn(make_float2(xb[t].z, xb[t].w));
        *(s16x4*)&smem[xb_base + r*128 + (kq ^ ((r & 7) << 3))] = w.s;
      }
      // issue next chunk's loads (xb free now); they fly during GEMM
      {
        int nit = it, ncb = cb + 1;
        if (ncb == 2){ ncb = 0; nit = it + GRID_A; }
        if (nit < NTASKS){
          const int nb0 = nit*16 + wv*4;
          const float* src = x + (size_t)nb0*1024 + ncb*128;
          #pragma unroll
          for (int t = 0; t < 8; ++t)
            xb[t] = *(const float4*)(src + (2*t + r_st)*256 + (lane & 31)*4);
        }
      }
      // GEMM over this chunk (K=128)
      #pragma unroll
      for (int kk = 0; kk < 4; ++kk){
        const int kl = kk*32 + g*8;
        const int kg = cb*128 + kl;
        s16x8 av = *(const s16x8*)&smem[xb_base + p*128 + (kl ^ ((p & 7) << 3))];
        #pragma unroll
        for (int ct = 0; ct < 4; ++ct){
          const int o = ct*16 + p;
          s16x8 bf = *(const s16x8*)&smem[o*256 + (kg ^ ((o & 7) << 3))];
          acc[ct] = __builtin_amdgcn_mfma_f32_16x16x32_bf16(av, bf, acc[ct], 0, 0, 0);
        }
      }
    }
    // epilogue: acc[ct][r] = Wh[graph b0+g][node r][col ct*16+p] -> [b][c][j] bf16
    unsigned short* wp = whT + (size_t)(b0 + g)*256;
    #pragma unroll
    for (int ct = 0; ct < 4; ++ct){
      union { s16x4 s; __hip_bfloat162 h2[2]; } w;
      w.h2[0] = __float22bfloat162_rn(make_float2(acc[ct][0], acc[ct][1]));
      w.h2[1] = __float22bfloat162_rn(make_float2(acc[ct][2], acc[ct][3]));
      *(s16x4*)(wp + (ct*16 + p)*4) = w.s;
    }
  }
}

// ================= Phase B: attention, one graph per 4 lanes =================
__launch_bounds__(256, 1)
__global__ void attn_kernel(const float* __restrict__ adj, const float* __restrict__ a,
                            const float* __restrict__ fc_b, const float* __restrict__ vf,
                            const unsigned short* __restrict__ whT,
                            float* __restrict__ out){
  const int tid = threadIdx.x;
  const int l  = tid & 3;
  const int b  = blockIdx.x*64 + (tid >> 2);
  const int qb = (tid & 63) & ~3;   // quad base lane within wave

  s16x8 w8[8];   // lane's 16 cols x 4 nodes of Wh (bf16): w8[t] = cols {2t,2t+1}
  {
    const s16x8* wp = (const s16x8*)(whT + (size_t)b*256 + l*64);
    #pragma unroll
    for (int t = 0; t < 8; ++t) w8[t] = wp[t];
  }
  float4 adjr = *(const float4*)(adj + (size_t)b*16 + l*4);   // adj row l
  float aS[16], aD[16], v1[16], v2[16], v3[16];
  #pragma unroll
  for (int t = 0; t < 4; ++t){
    *(float4*)&aS[t*4] = *(const float4*)(a +       l*16 + t*4);
    *(float4*)&aD[t*4] = *(const float4*)(a + 64 +  l*16 + t*4);
    *(float4*)&v1[t*4] = *(const float4*)(vf + 10240 + l*16 + t*4);
    *(float4*)&v2[t*4] = *(const float4*)(vf + 10304 + l*16 + t*4);
    *(float4*)&v3[t*4] = *(const float4*)(vf + 10368 + l*16 + t*4);
  }

  // fs[j] = Wh[j].aS, fd[j] = Wh[j].aD  (partial over lane cols, quad all-reduce)
  float fsp[4] = {0,0,0,0}, fdp[4] = {0,0,0,0};
  #pragma unroll
  for (int t = 0; t < 8; ++t){
    #pragma unroll
    for (int j = 0; j < 4; ++j){
      float w0 = bf2f(w8[t][j]), w1 = bf2f(w8[t][4+j]);
      fsp[j] += w0*aS[2*t] + w1*aS[2*t+1];
      fdp[j] += w0*aD[2*t] + w1*aD[2*t+1];
    }
  }
  #pragma unroll
  for (int m = 1; m < 4; m <<= 1){
    #pragma unroll
    for (int j = 0; j < 4; ++j){
      fsp[j] += __shfl_xor(fsp[j], m);
      fdp[j] += __shfl_xor(fdp[j], m);
    }
  }

  // layer-1 softmax: lane l owns e-row l (softmax axis local!)
  float fsl = (l & 2) ? ((l & 1) ? fsp[3] : fsp[2]) : ((l & 1) ? fsp[1] : fsp[0]);
  float e[4] = { fsl + fdp[0], fsl + fdp[1], fsl + fdp[2], fsl + fdp[3] };
  float am[4] = { adjr.x, adjr.y, adjr.z, adjr.w };
  #pragma unroll
  for (int j = 0; j < 4; ++j){
    e[j] = (e[j] > 0.f) ? e[j] : LRELU_ALPHA*e[j];
    e[j] = (am[j] > 0.f) ? e[j] : NEG_INF;
  }
  float mx = fmaxf(fmaxf(e[0], e[1]), fmaxf(e[2], e[3]));
  float attl[4]; float se = 0.f;
  #pragma unroll
  for (int j = 0; j < 4; ++j){ attl[j] = __expf(e[j] - mx); se += attl[j]; }
  float inv = 1.f / se;
  #pragma unroll
  for (int j = 0; j < 4; ++j) attl[j] *= inv;

  // all-gather att matrix into every quad lane
  float att[4][4];
  #pragma unroll
  for (int r = 0; r < 4; ++r){
    #pragma unroll
    for (int j = 0; j < 4; ++j) att[r][j] = __shfl(attl[j], qb + r);
  }

  // h1 = elu(att @ Wh) transient; dots with v1/v2/v3
  float sv[4], fd2[4], fs20 = 0.f;
  #pragma unroll
  for (int r = 0; r < 4; ++r){
    float s2 = 0.f, s3 = 0.f, s1 = 0.f;
    #pragma unroll
    for (int t = 0; t < 8; ++t){
      float hp0 = att[r][0]*bf2f(w8[t][0]) + att[r][1]*bf2f(w8[t][1])
                + att[r][2]*bf2f(w8[t][2]) + att[r][3]*bf2f(w8[t][3]);
      float hp1 = att[r][0]*bf2f(w8[t][4]) + att[r][1]*bf2f(w8[t][5])
                + att[r][2]*bf2f(w8[t][6]) + att[r][3]*bf2f(w8[t][7]);
      float h0 = (hp0 > 0.f) ? hp0 : (__expf(hp0) - 1.f);
      float h1 = (hp1 > 0.f) ? hp1 : (__expf(hp1) - 1.f);
      s2 += h0*v2[2*t] + h1*v2[2*t+1];
      s3 += h0*v3[2*t] + h1*v3[2*t+1];
      if (r == 0) s1 += h0*v1[2*t] + h1*v1[2*t+1];
    }
    fd2[r] = s2; sv[r] = s3;
    if (r == 0) fs20 = s1;
  }
  #pragma unroll
  for (int m = 1; m < 4; m <<= 1){
    #pragma unroll
    for (int r = 0; r < 4; ++r){
      fd2[r] += __shfl_xor(fd2[r], m);
      sv[r]  += __shfl_xor(sv[r],  m);
    }
    fs20 += __shfl_xor(fs20, m);
  }

  // layer-2 (row 0 only) + fc
  float a00 = __shfl(adjr.x, qb), a01 = __shfl(adjr.y, qb),
        a02 = __shfl(adjr.z, qb), a03 = __shfl(adjr.w, qb);
  float a0m[4] = { a00, a01, a02, a03 };
  float e2[4];
  #pragma unroll
  for (int j = 0; j < 4; ++j){
    float tv = fs20 + fd2[j];
    tv = (tv > 0.f) ? tv : LRELU_ALPHA*tv;
    e2[j] = (a0m[j] > 0.f) ? tv : NEG_INF;
  }
  float m2 = fmaxf(fmaxf(e2[0], e2[1]), fmaxf(e2[2], e2[3]));
  float s2s = 0.f, ov = 0.f;
  #pragma unroll
  for (int j = 0; j < 4; ++j){
    float pj = __expf(e2[j] - m2);
    s2s += pj; ov += pj*sv[j];
  }
  if (l == 0) out[b] = ov/s2s + fc_b[0];
}

// ================= Fallback (R8 kernel, proven-correct) =================
__launch_bounds__(256, 2)
__global__ void fb_kernel(const float* __restrict__ x, const float* __restrict__ adj,
                          const float* __restrict__ fc_b,
                          const unsigned short* __restrict__ wsp,
                          float* __restrict__ out){
  __shared__ __align__(16) unsigned short smem[36864];
  const int tid  = threadIdx.x;
  const int lane = tid & 63;
  const int p  = tid & 15;
  const int g  = (tid >> 4) & 3;
  const int wv = tid >> 6;
  const int lbase = tid & 48;
  const int xbase = 20480 + wv*4096;

  float4 xb[16];
  float adv;
  {
    const int b0 = blockIdx.x*16 + wv*4;
    const float* xsrc = x + (size_t)b0*1024 + lane*4;
    #pragma unroll
    for (int i = 0; i < 16; ++i) xb[i] = *(const float4*)(xsrc + i*256);
    adv = adj[(size_t)(b0 + g)*16 + p];
  }
  {
    const uint4* src = (const uint4*)wsp;
    uint4* dst = (uint4*)smem;
    #pragma unroll
    for (int i = 0; i < 10; ++i) dst[tid + 256*i] = src[tid + 256*i];
  }
  const float* vf = (const float*)wsp;
  float v1l[4], v2l[4], v3l[4];
  #pragma unroll
  for (int ct = 0; ct < 4; ++ct){
    v1l[ct] = vf[10240 +   0 + ct*16 + p];
    v2l[ct] = vf[10240 +  64 + ct*16 + p];
    v3l[ct] = vf[10240 + 128 + ct*16 + p];
  }
  const float fcb = fc_b[0];
  __syncthreads();

  for (int it = blockIdx.x; it < NTASKS; it += 512){
    const int b0 = it*16 + wv*4;
    const float adjv = adv;
    #pragma unroll
    for (int i = 0; i < 16; ++i){
      union { s16x4 s; __hip_bfloat162 h2[2]; } w;
      w.h2[0] = __float22bfloat162_rn(make_float2(xb[i].x, xb[i].y));
      w.h2[1] = __float22bfloat162_rn(make_float2(xb[i].z, xb[i].w));
      *(s16x4*)&smem[xbase + i*256 + ((lane*4) ^ ((i & 7) << 3))] = w.s;
    }
    f32x4 acc[4], acce;
    #pragma unroll
    for (int ct = 0; ct < 4; ++ct) acc[ct] = (f32x4){0.f,0.f,0.f,0.f};
    acce = (f32x4){0.f,0.f,0.f,0.f};
    #pragma unroll
    for (int kk = 0; kk < 8; ++kk){
      const int kb = kk*32 + g*8;
      s16x8 av = *(const s16x8*)&smem[xbase + p*256 + (kb ^ ((p & 7) << 3))];
      #pragma unroll
      for (int ct = 0; ct < 4; ++ct){
        const int o = ct*16 + p;
        s16x8 bf = *(const s16x8*)&smem[o*256 + (kb ^ ((o & 7) << 3))];
        acc[ct] = __builtin_amdgcn_mfma_f32_16x16x32_bf16(av, bf, acc[ct], 0, 0, 0);
      }
      s16x8 ef = *(const s16x8*)&smem[16384 + p*256 + (kb ^ ((p & 7) << 3))];
      acce = __builtin_amdgcn_mfma_f32_16x16x32_bf16(av, ef, acce, 0, 0, 0);
    }
    {
      const int itn = it + 512;
      if (itn < NTASKS){
        const int b0n = itn*16 + wv*4;
        const float* xsrc = x + (size_t)b0n*1024 + lane*4;
        #pragma unroll
        for (int i = 0; i < 16; ++i) xb[i] = *(const float4*)(xsrc + i*256);
        adv = adj[(size_t)(b0n + g)*16 + p];
      }
    }
    float fsr[4], fdr[4];
    #pragma unroll
    for (int r = 0; r < 4; ++r){
      fsr[r] = __shfl(acce[r], lbase + 0);
      fdr[r] = __shfl(acce[r], lbase + 1);
    }
    float fsi = (p & 8) ? ((p & 4) ? fsr[3] : fsr[2]) : ((p & 4) ? fsr[1] : fsr[0]);
    float fdj = (p & 2) ? ((p & 1) ? fdr[3] : fdr[2]) : ((p & 1) ? fdr[1] : fdr[0]);
    float ev = fsi + fdj;
    ev = (ev > 0.f) ? ev : LRELU_ALPHA*ev;
    ev = (adjv > 0.f) ? ev : NEG_INF;
    float mx = fmaxf(ev, __shfl_xor(ev, 1));
    mx = fmaxf(mx, __shfl_xor(mx, 2));
    float pe = __expf(ev - mx);
    float se = pe + __shfl_xor(pe, 1);
    se += __shfl_xor(se, 2);
    const float att = pe / se;
    float fd2[4], sv[4], fs20 = 0.f;
    #pragma unroll
    for (int r = 0; r < 4; ++r){
      float b0a = __shfl(att, lbase + r*4 + 0);
      float b1a = __shfl(att, lbase + r*4 + 1);
      float b2a = __shfl(att, lbase + r*4 + 2);
      float b3a = __shfl(att, lbase + r*4 + 3);
      float s1 = 0.f, s2 = 0.f, s0 = 0.f;
      #pragma unroll
      for (int ct = 0; ct < 4; ++ct){
        float hp = b0a*acc[ct][0] + b1a*acc[ct][1] + b2a*acc[ct][2] + b3a*acc[ct][3];
        float h1 = (hp > 0.f) ? hp : (__expf(hp) - 1.0f);
        s1 += h1*v2l[ct]; s2 += h1*v3l[ct];
        if (r == 0) s0 += h1*v1l[ct];
      }
      fd2[r] = s1; sv[r] = s2;
      if (r == 0) fs20 = s0;
    }
    #pragma unroll
    for (int msk = 1; msk < 16; msk <<= 1){
      #pragma unroll
      for (int r = 0; r < 4; ++r){
        fd2[r] += __shfl_xor(fd2[r], msk);
        sv[r]  += __shfl_xor(sv[r],  msk);
      }
      fs20 += __shfl_xor(fs20, msk);
    }
    float e2[4];
    #pragma unroll
    for (int j = 0; j < 4; ++j){
      float adj0 = __shfl(adjv, lbase + j);
      float tv = fs20 + fd2[j];
      tv = (tv > 0.f) ? tv : LRELU_ALPHA*tv;
      e2[j] = (adj0 > 0.f) ? tv : NEG_INF;
    }
    float m2 = fmaxf(fmaxf(e2[0], e2[1]), fmaxf(e2[2], e2[3]));
    float s2s = 0.f, ov = 0.f;
    #pragma unroll
    for (int j = 0; j < 4; ++j){
      float pj = __expf(e2[j] - m2);
      s2s += pj; ov += pj*sv[j];
    }
    if (p == 0) out[b0 + g] = ov/s2s + fcb;
  }
}

extern "C" void kernel_launch(void* const* d_in, const int* in_sizes, int n_in,
                              void* d_out, int out_size, void* d_ws, size_t ws_size,
                              hipStream_t stream){
  (void)in_sizes; (void)n_in; (void)out_size;
  const float* x   = (const float*)d_in[0];
  const float* adj = (const float*)d_in[1];
  const float* W   = (const float*)d_in[2];
  const float* a   = (const float*)d_in[3];
  const float* W2  = (const float*)d_in[4];
  const float* a2  = (const float*)d_in[5];
  const float* fcw = (const float*)d_in[6];
  const float* fcb = (const float*)d_in[7];
  float* out = (float*)d_out;
  unsigned short* wsp = (unsigned short*)d_ws;

  hipLaunchKernelGGL(prep_kernel, dim3(64), dim3(256), 0, stream, W, W2, a, a2, fcw, wsp);

  const size_t need = 65536 + (size_t)NB*512;
  if (ws_size >= need){
    unsigned short* whT = wsp + 32768;   // byte offset 65536
    hipLaunchKernelGGL(gemm_kernel, dim3(GRID_A), dim3(256), 0, stream, x, wsp, whT);
    hipLaunchKernelGGL(attn_kernel, dim3(NB/64), dim3(256), 0, stream,
                       adj, a, fcb, (const float*)wsp, whT, out);
  } else {
    hipLaunchKernelGGL(fb_kernel, dim3(512), dim3(256), 0, stream, x, adj, fcb, wsp, out);
  }
}

// Round 10
// 55.892 us; speedup vs baseline: 1.1423x; 1.1423x over previous
//
#include <hip/hip_runtime.h>
#include <hip/hip_bf16.h>
#include <stdint.h>

#define LRELU_ALPHA 0.2f
#define NEG_INF -9000000000000000.0f
#define NB 32768
#define NTASKS (NB/16)
#define GRID 512

typedef float f32x4 __attribute__((ext_vector_type(4)));
typedef short s16x8 __attribute__((ext_vector_type(8)));

__device__ __forceinline__ unsigned short f2bf(float f){
  unsigned int u = __float_as_uint(f);
  u += 0x7fffu + ((u >> 16) & 1u);   // round-to-nearest-even
  return (unsigned short)(u >> 16);
}

// ws layout: ushort [0,16384): W^T bf16 swizzled (64 cols x 256 k)
//            ushort [16384,20480): e-tile bf16 swizzled (16 cols x 256 k; col0=W@aS, col1=W@aD)
//            float  idx 10240..10432: v1,v2,v3 = W2eff @ {a2S, a2D, fc_w} (3 x 64 f32)
__global__ void prep_kernel(const float* __restrict__ W, const float* __restrict__ W2,
                            const float* __restrict__ a, const float* __restrict__ a2,
                            const float* __restrict__ fc_w,
                            unsigned short* __restrict__ wsp){
  int t = blockIdx.x * blockDim.x + threadIdx.x;
  if (t < 64*256){
    int o = t & 63, k = t >> 6;
    wsp[o*256 + (k ^ ((o & 7) << 3))] = f2bf(W[k*64 + o]);
  }
  if (t < 16*256){
    int o = t & 15, k = t >> 4;
    float v = 0.f;
    if (o == 0){ for (int c = 0; c < 64; ++c) v += W[k*64 + c]*a[c]; }
    else if (o == 1){ for (int c = 0; c < 64; ++c) v += W[k*64 + c]*a[64 + c]; }
    wsp[16384 + o*256 + (k ^ ((o & 7) << 3))] = f2bf(v);
  }
  if (t < 192){
    int which = t >> 6, c = t & 63;
    const float* vec = (which == 0) ? a2 : (which == 1) ? (a2 + 64) : fc_w;
    float s = 0.f;
    for (int o = 0; o < 64; ++o){
      float w2e = 0.f;
      #pragma unroll
      for (int h = 0; h < 8; ++h) w2e += W2[(h*64 + c)*64 + o];
      s += w2e * vec[o];
    }
    ((float*)wsp)[10240 + t] = s;
  }
}

// x staged via global_load_lds DMA (zero VGPR footprint -> no spill possible).
// Wave-private 8KB chunk buffer, K split in 2 chunks; per-wave vmcnt pipeline,
// NO barriers in the loop. Source-side XOR swizzle (slot s of row r holds
// global slot s^(r&7)) keeps both DMA (linear dest) and strided reads
// bank-balanced. LDS 72KB -> 2 blocks/CU, 8 waves/CU.
__launch_bounds__(256, 2)
__global__ void gat_kernel(const float* __restrict__ x, const float* __restrict__ adj,
                           const float* __restrict__ fc_b,
                           const unsigned short* __restrict__ wsp,
                           float* __restrict__ out){
  // ushort units: [0,16384) W^T ; [16384,20480) e-tile ; bytes 40960+ : x chunks (4 waves x 8KB)
  __shared__ __align__(16) unsigned short smem[36864];
  const int tid  = threadIdx.x;
  const int lane = tid & 63;
  const int p  = tid & 15;        // A-row / B-col / C-col lane index
  const int g  = (tid >> 4) & 3;  // k-slice group within wave
  const int wv = tid >> 6;        // wave id in block
  const int lbase = tid & 48;     // wave-relative group base lane
  const int lo = lane & 31, hi = lane >> 5;
  char* xbuf = ((char*)smem) + 40960 + wv*8192;

  // ---- stage W + e-tile into LDS (L2-resident source) ----
  {
    const uint4* src = (const uint4*)wsp;
    uint4* dst = (uint4*)smem;
    #pragma unroll
    for (int i = 0; i < 10; ++i) dst[tid + 256*i] = src[tid + 256*i];
  }
  // per-lane GEMV vectors for layer 2
  const float* vf = (const float*)wsp;
  float v1l[4], v2l[4], v3l[4];
  #pragma unroll
  for (int ct = 0; ct < 4; ++ct){
    v1l[ct] = vf[10240 +   0 + ct*16 + p];
    v2l[ct] = vf[10240 +  64 + ct*16 + p];
    v3l[ct] = vf[10240 + 128 + ct*16 + p];
  }
  const float fcb = fc_b[0];
  __syncthreads();   // the ONLY barrier

  // DMA one 8KB chunk (16 rows x 512B): instr i covers rows {2i, 2i+hi}.
  // LDS slot s of row r receives global 16B-slot s^(r&7).
  #define DMA_CHUNK(task, cb)                                                        \
    do {                                                                             \
      const char* gbase = (const char*)x + ((size_t)(task)*64 + wv*16)*1024 + (size_t)(cb)*512; \
      _Pragma("unroll")                                                              \
      for (int i = 0; i < 8; ++i){                                                   \
        const int r = 2*i + hi;                                                      \
        const int sw = lo ^ (r & 7);                                                 \
        const char* gp = gbase + (size_t)r*1024 + sw*16;                             \
        __builtin_amdgcn_global_load_lds(                                            \
            (const __attribute__((address_space(1))) void*)gp,                       \
            (__attribute__((address_space(3))) void*)(xbuf + i*1024), 16, 0, 0);     \
      }                                                                              \
    } while (0)

  // prologue: adj prefetch + first chunk DMA
  float adv = adj[(size_t)(blockIdx.x*16 + wv*4 + g)*16 + p];
  DMA_CHUNK(blockIdx.x, 0);

  for (int it = blockIdx.x; it < NTASKS; it += GRID){
    const float adjv = adv;
    f32x4 acc[4], acce;
    #pragma unroll
    for (int ct = 0; ct < 4; ++ct) acc[ct] = (f32x4){0.f,0.f,0.f,0.f};
    acce = (f32x4){0.f,0.f,0.f,0.f};

    #pragma unroll
    for (int cb = 0; cb < 2; ++cb){
      // wait for this chunk's DMA (issued one compute-phase ago)
      asm volatile("s_waitcnt vmcnt(0)" ::: "memory");
      // pull A-fragments (f32) into registers; buffer becomes free
      float4 fr[8];
      #pragma unroll
      for (int kk = 0; kk < 4; ++kk){
        #pragma unroll
        for (int j = 0; j < 2; ++j){
          const int sw = (kk*8 + g*2 + j) ^ (p & 7);
          fr[kk*2 + j] = *(const float4*)(xbuf + p*512 + sw*16);
        }
      }
      asm volatile("s_waitcnt lgkmcnt(0)" ::: "memory");
      __builtin_amdgcn_sched_barrier(0);
      // issue next chunk's DMA NOW; it flies under the MFMA/epilogue below
      if (cb == 0){
        DMA_CHUNK(it, 1);
      } else {
        const int itn = it + GRID;
        if (itn < NTASKS){
          DMA_CHUNK(itn, 0);
          adv = adj[(size_t)(itn*16 + wv*4 + g)*16 + p];
        }
      }
      // compute this chunk: cvt + MFMA
      #pragma unroll
      for (int kk = 0; kk < 4; ++kk){
        float4 f0 = fr[kk*2], f1 = fr[kk*2 + 1];
        union { s16x8 v; __hip_bfloat162 h2[4]; } af;
        af.h2[0] = __float22bfloat162_rn(make_float2(f0.x, f0.y));
        af.h2[1] = __float22bfloat162_rn(make_float2(f0.z, f0.w));
        af.h2[2] = __float22bfloat162_rn(make_float2(f1.x, f1.y));
        af.h2[3] = __float22bfloat162_rn(make_float2(f1.z, f1.w));
        const int kg = cb*128 + kk*32 + g*8;
        #pragma unroll
        for (int ct = 0; ct < 4; ++ct){
          const int o = ct*16 + p;
          s16x8 bf = *(const s16x8*)&smem[o*256 + (kg ^ ((o & 7) << 3))];
          acc[ct] = __builtin_amdgcn_mfma_f32_16x16x32_bf16(af.v, bf, acc[ct], 0, 0, 0);
        }
        s16x8 ef = *(const s16x8*)&smem[16384 + p*256 + (kg ^ ((p & 7) << 3))];
        acce = __builtin_amdgcn_mfma_f32_16x16x32_bf16(af.v, ef, acce, 0, 0, 0);
      }
    }
    // acc[ct][r] = Wh[4g+r][ct*16+p] ; acce[r] at lane(g,0)=fs[4g+r], lane(g,1)=fd[4g+r]

    // -------- layer-1 attention (group g = graph it*16+wv*4+g) --------
    float fsr[4], fdr[4];
    #pragma unroll
    for (int r = 0; r < 4; ++r){
      fsr[r] = __shfl(acce[r], lbase + 0);
      fdr[r] = __shfl(acce[r], lbase + 1);
    }
    float fsi = (p & 8) ? ((p & 4) ? fsr[3] : fsr[2]) : ((p & 4) ? fsr[1] : fsr[0]);
    float fdj = (p & 2) ? ((p & 1) ? fdr[3] : fdr[2]) : ((p & 1) ? fdr[1] : fdr[0]);
    float ev = fsi + fdj;
    ev = (ev > 0.f) ? ev : LRELU_ALPHA*ev;
    ev = (adjv > 0.f) ? ev : NEG_INF;
    float mx = fmaxf(ev, __shfl_xor(ev, 1));
    mx = fmaxf(mx, __shfl_xor(mx, 2));
    float pe = __expf(ev - mx);
    float se = pe + __shfl_xor(pe, 1);
    se += __shfl_xor(se, 2);
    const float att = pe / se;   // att[i=p>>2][j=p&3]

    // -------- hp = att @ Wh ; h1 = elu(hp) transient, folded into GEMVs --------
    float fd2[4], sv[4], fs20 = 0.f;
    #pragma unroll
    for (int r = 0; r < 4; ++r){
      float b0a = __shfl(att, lbase + r*4 + 0);
      float b1a = __shfl(att, lbase + r*4 + 1);
      float b2a = __shfl(att, lbase + r*4 + 2);
      float b3a = __shfl(att, lbase + r*4 + 3);
      float s1 = 0.f, s2 = 0.f, s0 = 0.f;
      #pragma unroll
      for (int ct = 0; ct < 4; ++ct){
        float hp = b0a*acc[ct][0] + b1a*acc[ct][1] + b2a*acc[ct][2] + b3a*acc[ct][3];
        float h1 = (hp > 0.f) ? hp : (__expf(hp) - 1.0f);
        s1 += h1*v2l[ct];
        s2 += h1*v3l[ct];
        if (r == 0) s0 += h1*v1l[ct];
      }
      fd2[r] = s1; sv[r] = s2;
      if (r == 0) fs20 = s0;
    }
    #pragma unroll
    for (int msk = 1; msk < 16; msk <<= 1){
      #pragma unroll
      for (int r = 0; r < 4; ++r){
        fd2[r] += __shfl_xor(fd2[r], msk);
        sv[r]  += __shfl_xor(sv[r],  msk);
      }
      fs20 += __shfl_xor(fs20, msk);
    }

    // -------- layer-2 attention (row 0 only) + fc --------
    float e2[4];
    #pragma unroll
    for (int j = 0; j < 4; ++j){
      float adj0 = __shfl(adjv, lbase + j);     // adj[b][0][j]
      float tv = fs20 + fd2[j];
      tv = (tv > 0.f) ? tv : LRELU_ALPHA*tv;
      e2[j] = (adj0 > 0.f) ? tv : NEG_INF;
    }
    float m2 = fmaxf(fmaxf(e2[0], e2[1]), fmaxf(e2[2], e2[3]));
    float s2s = 0.f, ov = 0.f;
    #pragma unroll
    for (int j = 0; j < 4; ++j){
      float pj = __expf(e2[j] - m2);
      s2s += pj; ov += pj*sv[j];
    }
    if (p == 0) out[it*16 + wv*4 + g] = ov/s2s + fcb;
  }
  #undef DMA_CHUNK
}

extern "C" void kernel_launch(void* const* d_in, const int* in_sizes, int n_in,
                              void* d_out, int out_size, void* d_ws, size_t ws_size,
                              hipStream_t stream){
  (void)in_sizes; (void)n_in; (void)out_size; (void)ws_size;
  const float* x   = (const float*)d_in[0];
  const float* adj = (const float*)d_in[1];
  const float* W   = (const float*)d_in[2];
  const float* a   = (const float*)d_in[3];
  const float* W2  = (const float*)d_in[4];
  const float* a2  = (const float*)d_in[5];
  const float* fcw = (const float*)d_in[6];
  const float* fcb = (const float*)d_in[7];
  float* out = (float*)d_out;
  unsigned short* wsp = (unsigned short*)d_ws;

  hipLaunchKernelGGL(prep_kernel, dim3(64), dim3(256), 0, stream, W, W2, a, a2, fcw, wsp);
  hipLaunchKernelGGL(gat_kernel, dim3(GRID), dim3(256), 0, stream,
                     x, adj, fcb, wsp, out);
}